// Round 1
// baseline (2352.114 us; speedup 1.0000x reference)
//
#include <hip/hip_runtime.h>

#define Nn 50000
#define Dd 128
#define Rr 8
#define Ee 800000
#define EDd 32
#define BN_EPS 1e-5f

// ---------------------------------------------------------------- edge prep
__global__ __launch_bounds__(256) void k_deg(const int* __restrict__ node_out,
                                             const int* __restrict__ relation,
                                             const float* __restrict__ w_in,
                                             int* __restrict__ nor,
                                             float* __restrict__ deg) {
    int e = blockIdx.x * 256 + threadIdx.x;
    if (e >= Ee) return;
    int idx = node_out[e] * Rr + relation[e];
    nor[e] = idx;
    unsafeAtomicAdd(deg + idx, w_in[e]);
}

__global__ __launch_bounds__(256) void k_ew(const float* __restrict__ w_in,
                                            const int* __restrict__ nor,
                                            const float* __restrict__ deg,
                                            float* __restrict__ ew) {
    int e = blockIdx.x * 256 + threadIdx.x;
    if (e >= Ee) return;
    ew[e] = w_in[e] / deg[nor[e]];
}

// ------------------------------------------------- fused edge aggregate
// msg[e] = ew[e] * (src[node_in[e]] + ef[e] @ We + be); u[nor[e]] += msg
// One wave (64 lanes) per edge; 2 columns per lane; We staged in LDS.
__global__ __launch_bounds__(256) void k_aggregate(const float* __restrict__ src,
                                                   const int* __restrict__ node_in,
                                                   const int* __restrict__ nor,
                                                   const float* __restrict__ ew,
                                                   const float* __restrict__ ef,
                                                   const float* __restrict__ We,
                                                   const float* __restrict__ be,
                                                   float* __restrict__ u) {
    __shared__ float Ws[EDd][Dd];   // 16 KB
    __shared__ float bs[Dd];
    for (int i = threadIdx.x; i < EDd * Dd; i += 256) Ws[i >> 7][i & 127] = We[i];
    if (threadIdx.x < Dd) bs[threadIdx.x] = be[threadIdx.x];
    __syncthreads();

    int wave = threadIdx.x >> 6;
    int lane = threadIdx.x & 63;
    int d0 = lane * 2;

    for (long e = blockIdx.x * 4 + wave; e < Ee; e += (long)gridDim.x * 4) {
        int ni  = node_in[e];
        int idx = nor[e];
        float w = ew[e];
        float efv = ef[e * EDd + (lane & 31)];   // lanes 0..31 hold ef[0..31]
        float p0 = bs[d0], p1 = bs[d0 + 1];
        #pragma unroll
        for (int k = 0; k < EDd; ++k) {
            float f = __shfl(efv, k, 64);
            float2 wv = *(const float2*)&Ws[k][d0];
            p0 = fmaf(f, wv.x, p0);
            p1 = fmaf(f, wv.y, p1);
        }
        float2 xv = *(const float2*)(src + (long)ni * Dd + d0);
        float* up = u + (long)idx * Dd + d0;
        unsafeAtomicAdd(up,     w * (xv.x + p0));
        unsafeAtomicAdd(up + 1, w * (xv.y + p1));
    }
}

// ---------------------------------------------------------------- fp32 GEMM
// C[M,128] = mapA(A)[M,K] @ B[K,128] + bias (+ addrow[m%N] if HASADD) (+ C if ACC)
// PERM: A row for output row m is (m%N)*R + m/N  (layer-2 transpose fold-in)
template <bool ACC, bool PERM, bool HASADD>
__global__ __launch_bounds__(256) void k_gemm(const float* __restrict__ A,
                                              const float* __restrict__ B,
                                              const float* __restrict__ bias,
                                              const float* __restrict__ addrow,
                                              float* __restrict__ C,
                                              int M, int K) {
    __shared__ float As[32][68];    // transposed A tile, padded
    __shared__ float Bs[32][128];
    int tid = threadIdx.x;
    int tx = tid & 31;              // column quad: cols tx*4..+3
    int ty = tid >> 5;              // row octet: rows ty*8..+7
    int m0 = blockIdx.x * 64;

    float acc[8][4] = {};

    int a_row = tid >> 3;           // 0..31
    int a_c4  = (tid & 7) * 4;
    int b_row = tid >> 5;           // 0..7
    int b_c4  = (tid & 31) * 4;

    long arow_off[2];
    #pragma unroll
    for (int p = 0; p < 2; ++p) {
        int m = m0 + a_row + p * 32;
        if (m >= M) m = M - 1;
        long ar = PERM ? ((long)(m % Nn) * Rr + (m / Nn)) : (long)m;
        arow_off[p] = ar * (long)K;
    }

    for (int k0 = 0; k0 < K; k0 += 32) {
        __syncthreads();
        #pragma unroll
        for (int p = 0; p < 2; ++p) {
            float4 v = *(const float4*)(A + arow_off[p] + k0 + a_c4);
            int row = a_row + p * 32;
            As[a_c4 + 0][row] = v.x;
            As[a_c4 + 1][row] = v.y;
            As[a_c4 + 2][row] = v.z;
            As[a_c4 + 3][row] = v.w;
        }
        #pragma unroll
        for (int p = 0; p < 4; ++p) {
            int row = b_row + p * 8;
            *(float4*)&Bs[row][b_c4] = *(const float4*)(B + (long)(k0 + row) * Dd + b_c4);
        }
        __syncthreads();
        #pragma unroll
        for (int kk = 0; kk < 32; ++kk) {
            float4 b4  = *(float4*)&Bs[kk][tx * 4];
            float4 a40 = *(float4*)&As[kk][ty * 8];
            float4 a41 = *(float4*)&As[kk][ty * 8 + 4];
            float av[8] = {a40.x, a40.y, a40.z, a40.w, a41.x, a41.y, a41.z, a41.w};
            #pragma unroll
            for (int i = 0; i < 8; ++i) {
                acc[i][0] = fmaf(av[i], b4.x, acc[i][0]);
                acc[i][1] = fmaf(av[i], b4.y, acc[i][1]);
                acc[i][2] = fmaf(av[i], b4.z, acc[i][2]);
                acc[i][3] = fmaf(av[i], b4.w, acc[i][3]);
            }
        }
    }

    float4 bias4 = *(const float4*)(bias + tx * 4);
    #pragma unroll
    for (int i = 0; i < 8; ++i) {
        int m = m0 + ty * 8 + i;
        if (m >= M) break;
        float4 r;
        r.x = acc[i][0] + bias4.x;
        r.y = acc[i][1] + bias4.y;
        r.z = acc[i][2] + bias4.z;
        r.w = acc[i][3] + bias4.w;
        if (HASADD) {
            float4 s4 = *(const float4*)(addrow + (long)(m % Nn) * Dd + tx * 4);
            r.x += s4.x; r.y += s4.y; r.z += s4.z; r.w += s4.w;
        }
        if (ACC) {
            float4 c4 = *(const float4*)(C + (long)m * Dd + tx * 4);
            r.x += c4.x; r.y += c4.y; r.z += c4.z; r.w += c4.w;
        }
        *(float4*)(C + (long)m * Dd + tx * 4) = r;
    }
}

// ---------------------------------------------------------------- batchnorm
__global__ __launch_bounds__(256) void k_bn_stats(const float* __restrict__ X, int M,
                                                  float* __restrict__ stats) {
    int c  = (threadIdx.x & 31) * 4;
    int rh = threadIdx.x >> 5;      // 0..7
    float sx = 0, sy = 0, sz = 0, sw = 0;
    float qx = 0, qy = 0, qz = 0, qw = 0;
    for (long r = blockIdx.x * 8 + rh; r < M; r += (long)gridDim.x * 8) {
        float4 v = *(const float4*)(X + r * Dd + c);
        sx += v.x; sy += v.y; sz += v.z; sw += v.w;
        qx = fmaf(v.x, v.x, qx); qy = fmaf(v.y, v.y, qy);
        qz = fmaf(v.z, v.z, qz); qw = fmaf(v.w, v.w, qw);
    }
    __shared__ float RS[8][Dd];
    __shared__ float RQ[8][Dd];
    RS[rh][c] = sx; RS[rh][c + 1] = sy; RS[rh][c + 2] = sz; RS[rh][c + 3] = sw;
    RQ[rh][c] = qx; RQ[rh][c + 1] = qy; RQ[rh][c + 2] = qz; RQ[rh][c + 3] = qw;
    __syncthreads();
    if (threadIdx.x < Dd) {
        int d = threadIdx.x;
        float t = 0, q = 0;
        #pragma unroll
        for (int j = 0; j < 8; ++j) { t += RS[j][d]; q += RQ[j][d]; }
        unsafeAtomicAdd(stats + d, t);
        unsafeAtomicAdd(stats + Dd + d, q);
    }
}

__global__ __launch_bounds__(256) void k_bn_apply(float* __restrict__ X,
                                                  const float* __restrict__ stats,
                                                  const float* __restrict__ g,
                                                  const float* __restrict__ b, int M) {
    int c  = (threadIdx.x & 31) * 4;
    int rh = threadIdx.x >> 5;
    float invM = 1.0f / (float)M;
    float4 s4 = *(const float4*)(stats + c);
    float4 q4 = *(const float4*)(stats + Dd + c);
    float4 g4 = *(const float4*)(g + c);
    float4 b4 = *(const float4*)(b + c);
    float m0 = s4.x * invM, m1 = s4.y * invM, m2 = s4.z * invM, m3 = s4.w * invM;
    float sc0 = g4.x / sqrtf(q4.x * invM - m0 * m0 + BN_EPS);
    float sc1 = g4.y / sqrtf(q4.y * invM - m1 * m1 + BN_EPS);
    float sc2 = g4.z / sqrtf(q4.z * invM - m2 * m2 + BN_EPS);
    float sc3 = g4.w / sqrtf(q4.w * invM - m3 * m3 + BN_EPS);
    float sh0 = b4.x - m0 * sc0, sh1 = b4.y - m1 * sc1;
    float sh2 = b4.z - m2 * sc2, sh3 = b4.w - m3 * sc3;
    for (long r = blockIdx.x * 8 + rh; r < M; r += (long)gridDim.x * 8) {
        float4 v = *(float4*)(X + r * Dd + c);
        v.x = fmaxf(fmaf(v.x, sc0, sh0), 0.f);
        v.y = fmaxf(fmaf(v.y, sc1, sh1), 0.f);
        v.z = fmaxf(fmaf(v.z, sc2, sh2), 0.f);
        v.w = fmaxf(fmaf(v.w, sc3, sh3), 0.f);
        *(float4*)(X + r * Dd + c) = v;
    }
}

// ---------------------------------------------------------------- launch
extern "C" void kernel_launch(void* const* d_in, const int* in_sizes, int n_in,
                              void* d_out, int out_size, void* d_ws, size_t ws_size,
                              hipStream_t stream) {
    const float* x            = (const float*)d_in[0];
    const int*   node_in      = (const int*)d_in[1];
    const int*   node_out     = (const int*)d_in[2];
    const int*   relation     = (const int*)d_in[3];
    const float* edge_weight  = (const float*)d_in[4];
    const float* edge_feature = (const float*)d_in[5];
    const float* l1_Wlin  = (const float*)d_in[6];
    const float* l1_blin  = (const float*)d_in[7];
    const float* l1_Wself = (const float*)d_in[8];
    const float* l1_bself = (const float*)d_in[9];
    const float* l1_Wedge = (const float*)d_in[10];
    const float* l1_bedge = (const float*)d_in[11];
    const float* l1_g     = (const float*)d_in[12];
    const float* l1_b     = (const float*)d_in[13];
    const float* l2_Wlin  = (const float*)d_in[14];
    const float* l2_blin  = (const float*)d_in[15];
    const float* l2_Wself = (const float*)d_in[16];
    const float* l2_bself = (const float*)d_in[17];
    const float* l2_Wedge = (const float*)d_in[18];
    const float* l2_bedge = (const float*)d_in[19];
    const float* l2_g     = (const float*)d_in[20];
    const float* l2_b     = (const float*)d_in[21];
    float* out = (float*)d_out;

    // workspace layout (floats)
    float* u     = (float*)d_ws;                    // N*R*D  = 51,200,000
    float* h     = u + (long)Nn * Rr * Dd;          // N*D    =  6,400,000
    float* s     = h + (long)Nn * Dd;               // N*D    =  6,400,000
    float* deg   = s + (long)Nn * Dd;               // N*R    =    400,000
    float* ew    = deg + (long)Nn * Rr;             // E      =    800,000
    float* stats = ew + Ee;                         // 256
    int*   nor   = (int*)(stats + 256);             // E ints

    // ---- edge prep
    hipMemsetAsync(deg, 0, sizeof(float) * (long)Nn * Rr, stream);
    hipMemsetAsync(u, 0, sizeof(float) * (long)Nn * Rr * Dd, stream);
    hipMemsetAsync(stats, 0, sizeof(float) * 256, stream);
    k_deg<<<(Ee + 255) / 256, 256, 0, stream>>>(node_out, relation, edge_weight, nor, deg);
    k_ew<<<(Ee + 255) / 256, 256, 0, stream>>>(edge_weight, nor, deg, ew);

    // ---- layer 1
    k_aggregate<<<4096, 256, 0, stream>>>(x, node_in, nor, ew, edge_feature,
                                          l1_Wedge, l1_bedge, u);
    k_gemm<false, false, false><<<(Nn + 63) / 64, 256, 0, stream>>>(
        u, l1_Wlin, l1_blin, nullptr, h, Nn, Rr * Dd);
    k_gemm<true, false, false><<<(Nn + 63) / 64, 256, 0, stream>>>(
        x, l1_Wself, l1_bself, nullptr, h, Nn, Dd);
    k_bn_stats<<<1024, 256, 0, stream>>>(h, Nn, stats);
    k_bn_apply<<<1024, 256, 0, stream>>>(h, stats, l1_g, l1_b, Nn);

    // ---- layer 2
    hipMemsetAsync(u, 0, sizeof(float) * (long)Nn * Rr * Dd, stream);
    hipMemsetAsync(stats, 0, sizeof(float) * 256, stream);
    k_aggregate<<<4096, 256, 0, stream>>>(h, node_in, nor, ew, edge_feature,
                                          l2_Wedge, l2_bedge, u);
    k_gemm<false, false, false><<<(Nn + 63) / 64, 256, 0, stream>>>(
        h, l2_Wself, l2_bself, nullptr, s, Nn, Dd);
    // writes d_out in final (R,N,D) layout via PERM row mapping
    k_gemm<false, true, true><<<(Nn * Rr) / 64, 256, 0, stream>>>(
        u, l2_Wlin, l2_blin, s, out, Nn * Rr, Dd);
    k_bn_stats<<<2048, 256, 0, stream>>>(out, Nn * Rr, stats);
    k_bn_apply<<<2048, 256, 0, stream>>>(out, stats, l2_g, l2_b, Nn * Rr);
}

// Round 2
// 2084.041 us; speedup vs baseline: 1.1286x; 1.1286x over previous
//
#include <hip/hip_runtime.h>
#include <hip/hip_bf16.h>

#define Nn 50000
#define Dd 128
#define Rr 8
#define Ee 800000
#define EDd 32
#define NR (Nn * Rr)
#define BN_EPS 1e-5f

// ---------------------------------------------------------------- degree + histogram
__global__ __launch_bounds__(256) void k_deg(const int* __restrict__ node_out,
                                             const int* __restrict__ relation,
                                             const float* __restrict__ w_in,
                                             float* __restrict__ deg,
                                             int* __restrict__ cnt) {
    int e = blockIdx.x * 256 + threadIdx.x;
    if (e >= Ee) return;
    int idx = node_out[e] * Rr + relation[e];
    unsafeAtomicAdd(deg + idx, w_in[e]);
    atomicAdd(cnt + idx, 1);
}

// ---------------------------------------------------------------- 3-kernel exclusive scan
__global__ __launch_bounds__(256) void k_scan1(const int* __restrict__ cnt,
                                               int* __restrict__ base,
                                               int* __restrict__ partials) {
    __shared__ int sd[256];
    int b0 = blockIdx.x * 1024;
    int t = threadIdx.x;
    int v[4], s = 0;
    #pragma unroll
    for (int j = 0; j < 4; ++j) {
        int idx = b0 + t * 4 + j;
        v[j] = (idx < NR) ? cnt[idx] : 0;
        s += v[j];
    }
    sd[t] = s;
    __syncthreads();
    for (int off = 1; off < 256; off <<= 1) {
        int xv = (t >= off) ? sd[t - off] : 0;
        __syncthreads();
        sd[t] += xv;
        __syncthreads();
    }
    int excl = sd[t] - s;
    if (t == 255) partials[blockIdx.x] = sd[255];
    int run = excl;
    #pragma unroll
    for (int j = 0; j < 4; ++j) {
        int idx = b0 + t * 4 + j;
        if (idx < NR) base[idx] = run;
        run += v[j];
    }
}

__global__ __launch_bounds__(512) void k_scan2(int* __restrict__ partials, int n) {
    __shared__ int sd[512];
    int t = threadIdx.x;
    int own = (t < n) ? partials[t] : 0;
    sd[t] = own;
    __syncthreads();
    for (int off = 1; off < 512; off <<= 1) {
        int xv = (t >= off) ? sd[t - off] : 0;
        __syncthreads();
        sd[t] += xv;
        __syncthreads();
    }
    if (t < n) partials[t] = sd[t] - own;
}

__global__ __launch_bounds__(256) void k_scan3(int* __restrict__ base,
                                               const int* __restrict__ partials) {
    int b0 = blockIdx.x * 1024;
    int add = partials[blockIdx.x];
    int t = threadIdx.x;
    #pragma unroll
    for (int j = 0; j < 4; ++j) {
        int idx = b0 + t * 4 + j;
        if (idx < NR) base[idx] += add;
    }
}

// ---------------------------------------------------------------- scatter (counting sort)
// base becomes END offsets after this pass; segment = [base[d]-cnt[d], base[d])
__global__ __launch_bounds__(256) void k_scatter(const int* __restrict__ node_in,
                                                 const int* __restrict__ node_out,
                                                 const int* __restrict__ relation,
                                                 const float* __restrict__ w_in,
                                                 const float* __restrict__ deg,
                                                 int* __restrict__ base,
                                                 int* __restrict__ ni_s,
                                                 float* __restrict__ ew_s) {
    int e = blockIdx.x * 256 + threadIdx.x;
    if (e >= Ee) return;
    int idx = node_out[e] * Rr + relation[e];
    int pos = atomicAdd(base + idx, 1);
    ni_s[pos] = node_in[e];
    ew_s[pos] = w_in[e] / deg[idx];
}

// ---------------------------------------------------------------- agg_ef = segsum(ew * ef)
// half-wave (32 lanes) per edge; atomic into fp32 temp (u head, zeroed)
__global__ __launch_bounds__(256) void k_aggef(const int* __restrict__ node_out,
                                               const int* __restrict__ relation,
                                               const float* __restrict__ w_in,
                                               const float* __restrict__ deg,
                                               const float* __restrict__ ef,
                                               float* __restrict__ agg_f32) {
    int t = threadIdx.x;
    int l = t & 31;
    long e = (long)blockIdx.x * 8 + (t >> 5);
    if (e >= Ee) return;
    int idx = node_out[e] * Rr + relation[e];
    float w = w_in[e] / deg[idx];
    float v = ef[e * EDd + l];
    unsafeAtomicAdd(agg_f32 + (long)idx * EDd + l, w * v);
}

__global__ __launch_bounds__(256) void k_cvt(const float* __restrict__ src,
                                             __hip_bfloat16* __restrict__ dst) {
    long i = ((long)blockIdx.x * 256 + threadIdx.x) * 4;
    if (i >= (long)NR * EDd) return;
    float4 v = *(const float4*)(src + i);
    __hip_bfloat16 b0 = __float2bfloat16(v.x);
    __hip_bfloat16 b1 = __float2bfloat16(v.y);
    __hip_bfloat16 b2 = __float2bfloat16(v.z);
    __hip_bfloat16 b3 = __float2bfloat16(v.w);
    ushort4 o;
    o.x = *(unsigned short*)&b0; o.y = *(unsigned short*)&b1;
    o.z = *(unsigned short*)&b2; o.w = *(unsigned short*)&b3;
    *(ushort4*)(dst + i) = o;
}

// ---------------------------------------------------------------- CSR aggregate
// u[d] = sum_{e in seg(d)} ew*src[ni] + aggef[d]@We + (cnt>0)*be ; one wave per dest
__global__ __launch_bounds__(256) void k_agg(const float* __restrict__ src,
                                             const int* __restrict__ base_end,
                                             const int* __restrict__ cnt,
                                             const int* __restrict__ ni_s,
                                             const float* __restrict__ ew_s,
                                             const __hip_bfloat16* __restrict__ aggef,
                                             const float* __restrict__ We,
                                             const float* __restrict__ be,
                                             float* __restrict__ u) {
    __shared__ float Ws[EDd][Dd];   // 16 KB
    __shared__ float bs[Dd];
    for (int i = threadIdx.x; i < EDd * Dd; i += 256) Ws[i >> 7][i & 127] = We[i];
    if (threadIdx.x < Dd) bs[threadIdx.x] = be[threadIdx.x];
    __syncthreads();

    int wave = threadIdx.x >> 6;
    int lane = threadIdx.x & 63;
    int d0 = lane * 2;

    for (long d = blockIdx.x * 4 + wave; d < NR; d += (long)gridDim.x * 4) {
        int end = base_end[d];
        int c = cnt[d];
        float a0 = 0.f, a1 = 0.f;
        for (int e = end - c; e < end; ++e) {
            int ni = ni_s[e];
            float w = ew_s[e];
            float2 xv = *(const float2*)(src + (long)ni * Dd + d0);
            a0 = fmaf(w, xv.x, a0);
            a1 = fmaf(w, xv.y, a1);
        }
        float efv = __bfloat162float(aggef[d * EDd + (lane & 31)]);
        float p0, p1;
        if (c > 0) { p0 = bs[d0]; p1 = bs[d0 + 1]; } else { p0 = 0.f; p1 = 0.f; }
        #pragma unroll
        for (int k = 0; k < EDd; ++k) {
            float f = __shfl(efv, k, 64);
            float2 wv = *(const float2*)&Ws[k][d0];
            p0 = fmaf(f, wv.x, p0);
            p1 = fmaf(f, wv.y, p1);
        }
        *(float2*)(u + d * Dd + d0) = make_float2(a0 + p0, a1 + p1);
    }
}

// ---------------------------------------------------------------- dual-source fp32 GEMM
// C[m] = A1row(m)[K1] @ B1 + A2row(m)[128] @ B2 + bias1 + bias2
// A1row = PERM ? (m%N)*R + m/N : m ; A2row = PERM ? m%N : m
// STATS: column sum/sumsq of (pre-ReLU) outputs atomically into stats[0:128],[128:256]
template <bool PERM, bool STATS>
__global__ __launch_bounds__(256) void k_gemm2(const float* __restrict__ A1,
                                               const float* __restrict__ B1,
                                               const float* __restrict__ A2,
                                               const float* __restrict__ B2,
                                               const float* __restrict__ bias1,
                                               const float* __restrict__ bias2,
                                               float* __restrict__ C,
                                               float* __restrict__ stats,
                                               int M, int K1) {
    __shared__ float As[32][68];
    __shared__ float Bs[32][128];
    int tid = threadIdx.x;
    int tx = tid & 31;
    int ty = tid >> 5;
    int m0 = blockIdx.x * 64;

    float acc[8][4] = {};

    int a_row = tid >> 3;
    int a_c4  = (tid & 7) * 4;
    int b_row = tid >> 5;
    int b_c4  = (tid & 31) * 4;

    long arow1[2], arow2[2];
    #pragma unroll
    for (int p = 0; p < 2; ++p) {
        int m = m0 + a_row + p * 32;
        if (m >= M) m = M - 1;
        long r1 = PERM ? ((long)(m % Nn) * Rr + (m / Nn)) : (long)m;
        long r2 = PERM ? (long)(m % Nn) : (long)m;
        arow1[p] = r1 * (long)K1;
        arow2[p] = r2 * (long)Dd;
    }

    // ---- K1 loop (A1/B1)
    for (int k0 = 0; k0 < K1; k0 += 32) {
        __syncthreads();
        #pragma unroll
        for (int p = 0; p < 2; ++p) {
            float4 v = *(const float4*)(A1 + arow1[p] + k0 + a_c4);
            int row = a_row + p * 32;
            As[a_c4 + 0][row] = v.x; As[a_c4 + 1][row] = v.y;
            As[a_c4 + 2][row] = v.z; As[a_c4 + 3][row] = v.w;
        }
        #pragma unroll
        for (int p = 0; p < 4; ++p) {
            int row = b_row + p * 8;
            *(float4*)&Bs[row][b_c4] = *(const float4*)(B1 + (long)(k0 + row) * Dd + b_c4);
        }
        __syncthreads();
        #pragma unroll
        for (int kk = 0; kk < 32; ++kk) {
            float4 b4  = *(float4*)&Bs[kk][tx * 4];
            float4 a40 = *(float4*)&As[kk][ty * 8];
            float4 a41 = *(float4*)&As[kk][ty * 8 + 4];
            float av[8] = {a40.x, a40.y, a40.z, a40.w, a41.x, a41.y, a41.z, a41.w};
            #pragma unroll
            for (int i = 0; i < 8; ++i) {
                acc[i][0] = fmaf(av[i], b4.x, acc[i][0]);
                acc[i][1] = fmaf(av[i], b4.y, acc[i][1]);
                acc[i][2] = fmaf(av[i], b4.z, acc[i][2]);
                acc[i][3] = fmaf(av[i], b4.w, acc[i][3]);
            }
        }
    }

    // ---- K2 loop (A2/B2, K2 = 128)
    for (int k0 = 0; k0 < Dd; k0 += 32) {
        __syncthreads();
        #pragma unroll
        for (int p = 0; p < 2; ++p) {
            float4 v = *(const float4*)(A2 + arow2[p] + k0 + a_c4);
            int row = a_row + p * 32;
            As[a_c4 + 0][row] = v.x; As[a_c4 + 1][row] = v.y;
            As[a_c4 + 2][row] = v.z; As[a_c4 + 3][row] = v.w;
        }
        #pragma unroll
        for (int p = 0; p < 4; ++p) {
            int row = b_row + p * 8;
            *(float4*)&Bs[row][b_c4] = *(const float4*)(B2 + (long)(k0 + row) * Dd + b_c4);
        }
        __syncthreads();
        #pragma unroll
        for (int kk = 0; kk < 32; ++kk) {
            float4 b4  = *(float4*)&Bs[kk][tx * 4];
            float4 a40 = *(float4*)&As[kk][ty * 8];
            float4 a41 = *(float4*)&As[kk][ty * 8 + 4];
            float av[8] = {a40.x, a40.y, a40.z, a40.w, a41.x, a41.y, a41.z, a41.w};
            #pragma unroll
            for (int i = 0; i < 8; ++i) {
                acc[i][0] = fmaf(av[i], b4.x, acc[i][0]);
                acc[i][1] = fmaf(av[i], b4.y, acc[i][1]);
                acc[i][2] = fmaf(av[i], b4.z, acc[i][2]);
                acc[i][3] = fmaf(av[i], b4.w, acc[i][3]);
            }
        }
    }

    float4 b1v = *(const float4*)(bias1 + tx * 4);
    float4 b2v = *(const float4*)(bias2 + tx * 4);
    float bias4[4] = {b1v.x + b2v.x, b1v.y + b2v.y, b1v.z + b2v.z, b1v.w + b2v.w};

    float cs[4] = {0, 0, 0, 0}, cq[4] = {0, 0, 0, 0};
    #pragma unroll
    for (int i = 0; i < 8; ++i) {
        int m = m0 + ty * 8 + i;
        if (m >= M) break;
        float4 r;
        r.x = acc[i][0] + bias4[0];
        r.y = acc[i][1] + bias4[1];
        r.z = acc[i][2] + bias4[2];
        r.w = acc[i][3] + bias4[3];
        *(float4*)(C + (long)m * Dd + tx * 4) = r;
        if (STATS) {
            cs[0] += r.x; cs[1] += r.y; cs[2] += r.z; cs[3] += r.w;
            cq[0] = fmaf(r.x, r.x, cq[0]); cq[1] = fmaf(r.y, r.y, cq[1]);
            cq[2] = fmaf(r.z, r.z, cq[2]); cq[3] = fmaf(r.w, r.w, cq[3]);
        }
    }

    if (STATS) {
        __syncthreads();
        float* sumbuf = &As[0][0];   // reuse: 8 x 128
        float* sqbuf  = &Bs[0][0];
        #pragma unroll
        for (int j = 0; j < 4; ++j) {
            sumbuf[ty * Dd + tx * 4 + j] = cs[j];
            sqbuf[ty * Dd + tx * 4 + j]  = cq[j];
        }
        __syncthreads();
        if (tid < 32) {
            #pragma unroll
            for (int j = 0; j < 4; ++j) {
                int c = tid * 4 + j;
                float s = 0.f, q = 0.f;
                #pragma unroll
                for (int t = 0; t < 8; ++t) { s += sumbuf[t * Dd + c]; q += sqbuf[t * Dd + c]; }
                unsafeAtomicAdd(stats + c, s);
                unsafeAtomicAdd(stats + Dd + c, q);
            }
        }
    }
}

// ---------------------------------------------------------------- batchnorm apply (+ReLU)
__global__ __launch_bounds__(256) void k_bn_apply(float* __restrict__ X,
                                                  const float* __restrict__ stats,
                                                  const float* __restrict__ g,
                                                  const float* __restrict__ b, int M) {
    int c  = (threadIdx.x & 31) * 4;
    int rh = threadIdx.x >> 5;
    float invM = 1.0f / (float)M;
    float4 s4 = *(const float4*)(stats + c);
    float4 q4 = *(const float4*)(stats + Dd + c);
    float4 g4 = *(const float4*)(g + c);
    float4 b4 = *(const float4*)(b + c);
    float m0 = s4.x * invM, m1 = s4.y * invM, m2 = s4.z * invM, m3 = s4.w * invM;
    float sc0 = g4.x / sqrtf(q4.x * invM - m0 * m0 + BN_EPS);
    float sc1 = g4.y / sqrtf(q4.y * invM - m1 * m1 + BN_EPS);
    float sc2 = g4.z / sqrtf(q4.z * invM - m2 * m2 + BN_EPS);
    float sc3 = g4.w / sqrtf(q4.w * invM - m3 * m3 + BN_EPS);
    float sh0 = b4.x - m0 * sc0, sh1 = b4.y - m1 * sc1;
    float sh2 = b4.z - m2 * sc2, sh3 = b4.w - m3 * sc3;
    for (long r = blockIdx.x * 8 + rh; r < M; r += (long)gridDim.x * 8) {
        float4 v = *(float4*)(X + r * Dd + c);
        v.x = fmaxf(fmaf(v.x, sc0, sh0), 0.f);
        v.y = fmaxf(fmaf(v.y, sc1, sh1), 0.f);
        v.z = fmaxf(fmaf(v.z, sc2, sh2), 0.f);
        v.w = fmaxf(fmaf(v.w, sc3, sh3), 0.f);
        *(float4*)(X + r * Dd + c) = v;
    }
}

// ---------------------------------------------------------------- launch
extern "C" void kernel_launch(void* const* d_in, const int* in_sizes, int n_in,
                              void* d_out, int out_size, void* d_ws, size_t ws_size,
                              hipStream_t stream) {
    const float* x            = (const float*)d_in[0];
    const int*   node_in      = (const int*)d_in[1];
    const int*   node_out     = (const int*)d_in[2];
    const int*   relation     = (const int*)d_in[3];
    const float* edge_weight  = (const float*)d_in[4];
    const float* edge_feature = (const float*)d_in[5];
    const float* l1_Wlin  = (const float*)d_in[6];
    const float* l1_blin  = (const float*)d_in[7];
    const float* l1_Wself = (const float*)d_in[8];
    const float* l1_bself = (const float*)d_in[9];
    const float* l1_Wedge = (const float*)d_in[10];
    const float* l1_bedge = (const float*)d_in[11];
    const float* l1_g     = (const float*)d_in[12];
    const float* l1_b     = (const float*)d_in[13];
    const float* l2_Wlin  = (const float*)d_in[14];
    const float* l2_blin  = (const float*)d_in[15];
    const float* l2_Wself = (const float*)d_in[16];
    const float* l2_bself = (const float*)d_in[17];
    const float* l2_Wedge = (const float*)d_in[18];
    const float* l2_bedge = (const float*)d_in[19];
    const float* l2_g     = (const float*)d_in[20];
    const float* l2_b     = (const float*)d_in[21];
    float* out = (float*)d_out;

    // workspace layout (~267 MB)
    float* u     = (float*)d_ws;                       // NR*Dd floats; head reused as agg_ef fp32 temp
    float* h     = u + (long)NR * Dd;                  // Nn*Dd
    __hip_bfloat16* aggef = (__hip_bfloat16*)(h + (long)Nn * Dd);   // NR*EDd bf16
    float* deg   = (float*)(aggef + (long)NR * EDd);   // NR
    int*   cnt   = (int*)(deg + NR);                   // NR
    int*   base  = cnt + NR;                           // NR
    int*   ni_s  = base + NR;                          // Ee
    float* ew_s  = (float*)(ni_s + Ee);                // Ee
    int*   partials = (int*)(ew_s + Ee);               // 1024
    float* stats = (float*)(partials + 1024);          // 512

    const int NB1 = (NR + 1023) / 1024;                // 391

    // ---- prep
    hipMemsetAsync(deg, 0, sizeof(float) * NR, stream);
    hipMemsetAsync(cnt, 0, sizeof(int) * NR, stream);
    hipMemsetAsync(stats, 0, sizeof(float) * 512, stream);
    hipMemsetAsync(u, 0, sizeof(float) * (long)NR * EDd, stream);  // agg_ef fp32 temp
    k_deg<<<(Ee + 255) / 256, 256, 0, stream>>>(node_out, relation, edge_weight, deg, cnt);
    k_scan1<<<NB1, 256, 0, stream>>>(cnt, base, partials);
    k_scan2<<<1, 512, 0, stream>>>(partials, NB1);
    k_scan3<<<NB1, 256, 0, stream>>>(base, partials);
    k_scatter<<<(Ee + 255) / 256, 256, 0, stream>>>(node_in, node_out, relation, edge_weight,
                                                    deg, base, ni_s, ew_s);
    k_aggef<<<Ee / 8, 256, 0, stream>>>(node_out, relation, edge_weight, deg, edge_feature, u);
    k_cvt<<<((long)NR * EDd / 4 + 255) / 256, 256, 0, stream>>>(u, aggef);

    // ---- layer 1
    k_agg<<<4096, 256, 0, stream>>>(x, base, cnt, ni_s, ew_s, aggef, l1_Wedge, l1_bedge, u);
    k_gemm2<false, true><<<(Nn + 63) / 64, 256, 0, stream>>>(
        u, l1_Wlin, x, l1_Wself, l1_blin, l1_bself, h, stats, Nn, Rr * Dd);
    k_bn_apply<<<1024, 256, 0, stream>>>(h, stats, l1_g, l1_b, Nn);

    // ---- layer 2
    k_agg<<<4096, 256, 0, stream>>>(h, base, cnt, ni_s, ew_s, aggef, l2_Wedge, l2_bedge, u);
    k_gemm2<true, true><<<NR / 64, 256, 0, stream>>>(
        u, l2_Wlin, h, l2_Wself, l2_blin, l2_bself, out, stats + 256, NR, Dd);
    k_bn_apply<<<2048, 256, 0, stream>>>(out, stats + 256, l2_g, l2_b, NR);
}

// Round 3
// 1338.126 us; speedup vs baseline: 1.7578x; 1.5574x over previous
//
#include <hip/hip_runtime.h>
#include <hip/hip_bf16.h>

#define Nn 50000
#define Dd 128
#define Rr 8
#define Ee 800000
#define EDd 32
#define NR (Nn * Rr)
#define BN_EPS 1e-5f
#define NREP 16

typedef __attribute__((ext_vector_type(8))) short short8;
typedef __attribute__((ext_vector_type(4))) float floatx4;
typedef unsigned short u16;

__device__ inline float bf2f(u16 u) {
    unsigned int x = ((unsigned int)u) << 16;
    return __uint_as_float(x);
}
__device__ inline u16 f2bf(float f) {
    __hip_bfloat16 h = __float2bfloat16(f);
    return *(u16*)&h;
}

// ---------------------------------------------------------------- degree + histogram
__global__ __launch_bounds__(256) void k_deg(const int* __restrict__ node_out,
                                             const int* __restrict__ relation,
                                             const float* __restrict__ w_in,
                                             float* __restrict__ deg,
                                             int* __restrict__ cnt) {
    int e = blockIdx.x * 256 + threadIdx.x;
    if (e >= Ee) return;
    int idx = node_out[e] * Rr + relation[e];
    unsafeAtomicAdd(deg + idx, w_in[e]);
    atomicAdd(cnt + idx, 1);
}

// ---------------------------------------------------------------- 3-kernel exclusive scan
__global__ __launch_bounds__(256) void k_scan1(const int* __restrict__ cnt,
                                               int* __restrict__ base,
                                               int* __restrict__ partials) {
    __shared__ int sd[256];
    int b0 = blockIdx.x * 1024;
    int t = threadIdx.x;
    int v[4], s = 0;
    #pragma unroll
    for (int j = 0; j < 4; ++j) {
        int idx = b0 + t * 4 + j;
        v[j] = (idx < NR) ? cnt[idx] : 0;
        s += v[j];
    }
    sd[t] = s;
    __syncthreads();
    for (int off = 1; off < 256; off <<= 1) {
        int xv = (t >= off) ? sd[t - off] : 0;
        __syncthreads();
        sd[t] += xv;
        __syncthreads();
    }
    int excl = sd[t] - s;
    if (t == 255) partials[blockIdx.x] = sd[255];
    int run = excl;
    #pragma unroll
    for (int j = 0; j < 4; ++j) {
        int idx = b0 + t * 4 + j;
        if (idx < NR) base[idx] = run;
        run += v[j];
    }
}

__global__ __launch_bounds__(512) void k_scan2(int* __restrict__ partials, int n) {
    __shared__ int sd[512];
    int t = threadIdx.x;
    int own = (t < n) ? partials[t] : 0;
    sd[t] = own;
    __syncthreads();
    for (int off = 1; off < 512; off <<= 1) {
        int xv = (t >= off) ? sd[t - off] : 0;
        __syncthreads();
        sd[t] += xv;
        __syncthreads();
    }
    if (t < n) partials[t] = sd[t] - own;
}

__global__ __launch_bounds__(256) void k_scan3(int* __restrict__ base,
                                               const int* __restrict__ partials) {
    int b0 = blockIdx.x * 1024;
    int add = partials[blockIdx.x];
    int t = threadIdx.x;
    #pragma unroll
    for (int j = 0; j < 4; ++j) {
        int idx = b0 + t * 4 + j;
        if (idx < NR) base[idx] += add;
    }
}

// ---------------------------------------------------------------- scatter (counting sort)
__global__ __launch_bounds__(256) void k_scatter(const int* __restrict__ node_in,
                                                 const int* __restrict__ node_out,
                                                 const int* __restrict__ relation,
                                                 const float* __restrict__ w_in,
                                                 const float* __restrict__ deg,
                                                 int* __restrict__ base,
                                                 int* __restrict__ ni_s,
                                                 float* __restrict__ ew_s) {
    int e = blockIdx.x * 256 + threadIdx.x;
    if (e >= Ee) return;
    int idx = node_out[e] * Rr + relation[e];
    int pos = atomicAdd(base + idx, 1);
    ni_s[pos] = node_in[e];
    ew_s[pos] = w_in[e] / deg[idx];
}

// ---------------------------------------------------------------- agg_ef = segsum(ew * ef)
__global__ __launch_bounds__(256) void k_aggef(const int* __restrict__ node_out,
                                               const int* __restrict__ relation,
                                               const float* __restrict__ w_in,
                                               const float* __restrict__ deg,
                                               const float* __restrict__ ef,
                                               float* __restrict__ agg_f32) {
    int t = threadIdx.x;
    int l = t & 31;
    long e = (long)blockIdx.x * 8 + (t >> 5);
    if (e >= Ee) return;
    int idx = node_out[e] * Rr + relation[e];
    float w = w_in[e] / deg[idx];
    float v = ef[e * EDd + l];
    unsafeAtomicAdd(agg_f32 + (long)idx * EDd + l, w * v);
}

// ---------------------------------------------------------------- fp32 -> bf16 convert
__global__ __launch_bounds__(256) void k_cvt(const float* __restrict__ src,
                                             u16* __restrict__ dst, long n) {
    long i = ((long)blockIdx.x * 256 + threadIdx.x) * 4;
    if (i >= n) return;
    float4 v = *(const float4*)(src + i);
    ushort4 o;
    o.x = f2bf(v.x); o.y = f2bf(v.y); o.z = f2bf(v.z); o.w = f2bf(v.w);
    *(ushort4*)(dst + i) = o;
}

// ---------------------------------------------------------------- weight transpose
// Bt[p][n][k] bf16; p 0..7: l1_Wlin k-block p; p=8: l1_Wself; p=9: l2_Wlin; p=10: l2_Wself
__global__ __launch_bounds__(256) void k_prepB(const float* __restrict__ W1,
                                               const float* __restrict__ Ws1,
                                               const float* __restrict__ W2,
                                               const float* __restrict__ Ws2,
                                               u16* __restrict__ Bt) {
    int idx = blockIdx.x * 256 + threadIdx.x;
    if (idx >= 11 * 16384) return;
    int p = idx >> 14;
    int n = (idx >> 7) & 127;
    int k = idx & 127;
    float v;
    if (p < 8)       v = W1[((p << 7) + k) * 128 + n];
    else if (p == 8) v = Ws1[k * 128 + n];
    else if (p == 9) v = W2[k * 128 + n];
    else             v = Ws2[k * 128 + n];
    Bt[((long)p << 14) + n * 128 + k] = f2bf(v);
}

// ---------------------------------------------------------------- CSR aggregate (bf16 in/out)
__global__ __launch_bounds__(256) void k_agg(const u16* __restrict__ src,
                                             const int* __restrict__ base_end,
                                             const int* __restrict__ cnt,
                                             const int* __restrict__ ni_s,
                                             const float* __restrict__ ew_s,
                                             const u16* __restrict__ aggef,
                                             const float* __restrict__ We,
                                             const float* __restrict__ be,
                                             u16* __restrict__ u) {
    __shared__ float Ws[EDd][Dd];
    __shared__ float bs[Dd];
    for (int i = threadIdx.x; i < EDd * Dd; i += 256) Ws[i >> 7][i & 127] = We[i];
    if (threadIdx.x < Dd) bs[threadIdx.x] = be[threadIdx.x];
    __syncthreads();

    int wave = threadIdx.x >> 6;
    int lane = threadIdx.x & 63;
    int d0 = lane * 2;

    for (long d = blockIdx.x * 4 + wave; d < NR; d += (long)gridDim.x * 4) {
        int end = base_end[d];
        int c = cnt[d];
        float a0 = 0.f, a1 = 0.f;
        for (int e = end - c; e < end; ++e) {
            int ni = ni_s[e];
            float w = ew_s[e];
            ushort2 xv = *(const ushort2*)(src + (long)ni * Dd + d0);
            a0 = fmaf(w, bf2f(xv.x), a0);
            a1 = fmaf(w, bf2f(xv.y), a1);
        }
        float efv = bf2f(aggef[d * EDd + (lane & 31)]);
        float p0, p1;
        if (c > 0) { p0 = bs[d0]; p1 = bs[d0 + 1]; } else { p0 = 0.f; p1 = 0.f; }
        #pragma unroll
        for (int k = 0; k < EDd; ++k) {
            float f = __shfl(efv, k, 64);
            float2 wv = *(const float2*)&Ws[k][d0];
            p0 = fmaf(f, wv.x, p0);
            p1 = fmaf(f, wv.y, p1);
        }
        ushort2 o;
        o.x = f2bf(a0 + p0);
        o.y = f2bf(a1 + p1);
        *(ushort2*)(u + d * Dd + d0) = o;
    }
}

// ---------------------------------------------------------------- MFMA GEMM layer 1
// Hpre[m][128] = sum_{p<8} u[m*8+p][:] @ Bt[p] + x[m][:] @ Bt[8]   (bf16 out, fp32 stats)
// block: 256 thr, M-tile 64; wave tile 64m x 32n. A from global, B via padded LDS.
__global__ __launch_bounds__(256) void k_gemm_l1(const u16* __restrict__ U,
                                                 const u16* __restrict__ Xb,
                                                 const u16* __restrict__ Bt,
                                                 u16* __restrict__ Hpre,
                                                 float* __restrict__ stats) {
    __shared__ u16 Bs[128 * 136];
    const int tid = threadIdx.x;
    const int wave = tid >> 6, lane = tid & 63;
    const int l15 = lane & 15, kq = lane >> 4;
    const int kq8 = kq * 8;
    const int n0w = wave * 32;
    const int m0 = blockIdx.x * 64;

    floatx4 acc[4][2];
    #pragma unroll
    for (int i = 0; i < 4; ++i)
        #pragma unroll
        for (int j = 0; j < 2; ++j)
            acc[i][j] = (floatx4){0.f, 0.f, 0.f, 0.f};

    long mb[4];
    int mrow[4];
    #pragma unroll
    for (int ti = 0; ti < 4; ++ti) {
        int m = m0 + ti * 16 + l15;
        if (m >= Nn) m = Nn - 1;
        mrow[ti] = m;
        mb[ti] = (long)m * 1024;
    }

    const int stg_n = tid >> 1, stg_h = tid & 1;

    for (int p = 0; p < 9; ++p) {
        __syncthreads();
        {
            const u16* s = Bt + ((long)p << 14) + stg_n * 128 + stg_h * 64;
            u16* dptr = Bs + stg_n * 136 + stg_h * 64;
            #pragma unroll
            for (int j = 0; j < 8; ++j)
                *(uint4*)(dptr + j * 8) = *(const uint4*)(s + j * 8);
        }
        __syncthreads();

        const u16* Ap = (p < 8) ? U : Xb;
        long aoff[4];
        #pragma unroll
        for (int ti = 0; ti < 4; ++ti)
            aoff[ti] = (p < 8) ? (mb[ti] + p * 128) : ((long)mrow[ti] * 128);

        #pragma unroll
        for (int k0 = 0; k0 < 128; k0 += 32) {
            short8 a[4], b[2];
            #pragma unroll
            for (int ti = 0; ti < 4; ++ti)
                a[ti] = *(const short8*)(Ap + aoff[ti] + k0 + kq8);
            #pragma unroll
            for (int tj = 0; tj < 2; ++tj)
                b[tj] = *(const short8*)(Bs + (n0w + tj * 16 + l15) * 136 + k0 + kq8);
            #pragma unroll
            for (int ti = 0; ti < 4; ++ti)
                #pragma unroll
                for (int tj = 0; tj < 2; ++tj)
                    acc[ti][tj] = __builtin_amdgcn_mfma_f32_16x16x32_bf16(
                        a[ti], b[tj], acc[ti][tj], 0, 0, 0);
        }
    }

    float cs[2] = {0.f, 0.f}, cq[2] = {0.f, 0.f};
    #pragma unroll
    for (int ti = 0; ti < 4; ++ti) {
        #pragma unroll
        for (int r = 0; r < 4; ++r) {
            int m = m0 + ti * 16 + kq * 4 + r;
            if (m < Nn) {
                #pragma unroll
                for (int tj = 0; tj < 2; ++tj) {
                    float v = acc[ti][tj][r];
                    int col = n0w + tj * 16 + l15;
                    Hpre[(long)m * Dd + col] = f2bf(v);
                    cs[tj] += v;
                    cq[tj] = fmaf(v, v, cq[tj]);
                }
            }
        }
    }
    #pragma unroll
    for (int tj = 0; tj < 2; ++tj) {
        cs[tj] += __shfl_xor(cs[tj], 16, 64);
        cs[tj] += __shfl_xor(cs[tj], 32, 64);
        cq[tj] += __shfl_xor(cq[tj], 16, 64);
        cq[tj] += __shfl_xor(cq[tj], 32, 64);
    }
    if (kq == 0) {
        int rep = blockIdx.x & (NREP - 1);
        #pragma unroll
        for (int tj = 0; tj < 2; ++tj) {
            int col = n0w + tj * 16 + l15;
            unsafeAtomicAdd(stats + rep * 256 + col, cs[tj]);
            unsafeAtomicAdd(stats + rep * 256 + 128 + col, cq[tj]);
        }
    }
}

// ---------------------------------------------------------------- MFMA GEMM layer 2
// Out[r*N+n][128] = u[n*8+r] @ Bt2[0] + h[n] @ Bt2[1]   (fp32 out, fp32 stats)
// block: 256 thr, M-tile 128; wave tile 64m x 64n.
__global__ __launch_bounds__(256) void k_gemm_l2(const u16* __restrict__ U,
                                                 const u16* __restrict__ H,
                                                 const u16* __restrict__ Bt2,
                                                 float* __restrict__ Out,
                                                 float* __restrict__ stats) {
    __shared__ u16 Bs[128 * 136];
    const int tid = threadIdx.x;
    const int wave = tid >> 6, lane = tid & 63;
    const int l15 = lane & 15, kq = lane >> 4;
    const int kq8 = kq * 8;
    const int wm = wave & 1, wn = wave >> 1;
    const int n0w = wn * 64;
    const long m0 = (long)blockIdx.x * 128;

    floatx4 acc[4][4];
    #pragma unroll
    for (int i = 0; i < 4; ++i)
        #pragma unroll
        for (int j = 0; j < 4; ++j)
            acc[i][j] = (floatx4){0.f, 0.f, 0.f, 0.f};

    long aoffU[4], aoffH[4];
    #pragma unroll
    for (int ti = 0; ti < 4; ++ti) {
        long mm = m0 + wm * 64 + ti * 16 + l15;
        int n = (int)(mm % Nn);
        int r = (int)(mm / Nn);
        aoffU[ti] = ((long)n * 8 + r) * 128;
        aoffH[ti] = (long)n * 128;
    }

    const int stg_n = tid >> 1, stg_h = tid & 1;

    for (int p = 0; p < 2; ++p) {
        __syncthreads();
        {
            const u16* s = Bt2 + ((long)p << 14) + stg_n * 128 + stg_h * 64;
            u16* dptr = Bs + stg_n * 136 + stg_h * 64;
            #pragma unroll
            for (int j = 0; j < 8; ++j)
                *(uint4*)(dptr + j * 8) = *(const uint4*)(s + j * 8);
        }
        __syncthreads();

        const u16* Ap = p ? H : U;
        const long* ao = p ? aoffH : aoffU;

        #pragma unroll
        for (int k0 = 0; k0 < 128; k0 += 32) {
            short8 a[4], b[4];
            #pragma unroll
            for (int ti = 0; ti < 4; ++ti)
                a[ti] = *(const short8*)(Ap + ao[ti] + k0 + kq8);
            #pragma unroll
            for (int tj = 0; tj < 4; ++tj)
                b[tj] = *(const short8*)(Bs + (n0w + tj * 16 + l15) * 136 + k0 + kq8);
            #pragma unroll
            for (int ti = 0; ti < 4; ++ti)
                #pragma unroll
                for (int tj = 0; tj < 4; ++tj)
                    acc[ti][tj] = __builtin_amdgcn_mfma_f32_16x16x32_bf16(
                        a[ti], b[tj], acc[ti][tj], 0, 0, 0);
        }
    }

    float cs[4] = {0.f, 0.f, 0.f, 0.f}, cq[4] = {0.f, 0.f, 0.f, 0.f};
    #pragma unroll
    for (int ti = 0; ti < 4; ++ti) {
        #pragma unroll
        for (int r = 0; r < 4; ++r) {
            long mm = m0 + wm * 64 + ti * 16 + kq * 4 + r;
            #pragma unroll
            for (int tj = 0; tj < 4; ++tj) {
                float v = acc[ti][tj][r];
                int col = n0w + tj * 16 + l15;
                Out[mm * Dd + col] = v;
                cs[tj] += v;
                cq[tj] = fmaf(v, v, cq[tj]);
            }
        }
    }
    #pragma unroll
    for (int tj = 0; tj < 4; ++tj) {
        cs[tj] += __shfl_xor(cs[tj], 16, 64);
        cs[tj] += __shfl_xor(cs[tj], 32, 64);
        cq[tj] += __shfl_xor(cq[tj], 16, 64);
        cq[tj] += __shfl_xor(cq[tj], 32, 64);
    }
    if (kq == 0) {
        int rep = blockIdx.x & (NREP - 1);
        #pragma unroll
        for (int tj = 0; tj < 4; ++tj) {
            int col = n0w + tj * 16 + l15;
            unsafeAtomicAdd(stats + rep * 256 + col, cs[tj]);
            unsafeAtomicAdd(stats + rep * 256 + 128 + col, cq[tj]);
        }
    }
}

// ---------------------------------------------------------------- BN apply + ReLU (bf16 in/out)
__global__ __launch_bounds__(256) void k_bn_apply_bf(u16* __restrict__ X,
                                                     const float* __restrict__ stats,
                                                     const float* __restrict__ g,
                                                     const float* __restrict__ b, int M) {
    int c = (threadIdx.x & 31) * 4;
    int rh = threadIdx.x >> 5;
    float invM = 1.0f / (float)M;
    float s[4] = {0, 0, 0, 0}, q[4] = {0, 0, 0, 0};
    for (int rep = 0; rep < NREP; ++rep) {
        float4 s4 = *(const float4*)(stats + rep * 256 + c);
        float4 q4 = *(const float4*)(stats + rep * 256 + 128 + c);
        s[0] += s4.x; s[1] += s4.y; s[2] += s4.z; s[3] += s4.w;
        q[0] += q4.x; q[1] += q4.y; q[2] += q4.z; q[3] += q4.w;
    }
    float4 g4 = *(const float4*)(g + c);
    float4 b4 = *(const float4*)(b + c);
    float gv[4] = {g4.x, g4.y, g4.z, g4.w};
    float bv[4] = {b4.x, b4.y, b4.z, b4.w};
    float sc[4], sh[4];
    #pragma unroll
    for (int j = 0; j < 4; ++j) {
        float m = s[j] * invM;
        sc[j] = gv[j] / sqrtf(q[j] * invM - m * m + BN_EPS);
        sh[j] = bv[j] - m * sc[j];
    }
    for (long r = blockIdx.x * 8 + rh; r < M; r += (long)gridDim.x * 8) {
        ushort4 v = *(ushort4*)(X + r * Dd + c);
        ushort4 o;
        o.x = f2bf(fmaxf(fmaf(bf2f(v.x), sc[0], sh[0]), 0.f));
        o.y = f2bf(fmaxf(fmaf(bf2f(v.y), sc[1], sh[1]), 0.f));
        o.z = f2bf(fmaxf(fmaf(bf2f(v.z), sc[2], sh[2]), 0.f));
        o.w = f2bf(fmaxf(fmaf(bf2f(v.w), sc[3], sh[3]), 0.f));
        *(ushort4*)(X + r * Dd + c) = o;
    }
}

// ---------------------------------------------------------------- BN apply + ReLU (fp32 in-place)
__global__ __launch_bounds__(256) void k_bn_apply_f32(float* __restrict__ X,
                                                      const float* __restrict__ stats,
                                                      const float* __restrict__ g,
                                                      const float* __restrict__ b, int M) {
    int c = (threadIdx.x & 31) * 4;
    int rh = threadIdx.x >> 5;
    float invM = 1.0f / (float)M;
    float s[4] = {0, 0, 0, 0}, q[4] = {0, 0, 0, 0};
    for (int rep = 0; rep < NREP; ++rep) {
        float4 s4 = *(const float4*)(stats + rep * 256 + c);
        float4 q4 = *(const float4*)(stats + rep * 256 + 128 + c);
        s[0] += s4.x; s[1] += s4.y; s[2] += s4.z; s[3] += s4.w;
        q[0] += q4.x; q[1] += q4.y; q[2] += q4.z; q[3] += q4.w;
    }
    float4 g4 = *(const float4*)(g + c);
    float4 b4 = *(const float4*)(b + c);
    float gv[4] = {g4.x, g4.y, g4.z, g4.w};
    float bv[4] = {b4.x, b4.y, b4.z, b4.w};
    float sc[4], sh[4];
    #pragma unroll
    for (int j = 0; j < 4; ++j) {
        float m = s[j] * invM;
        sc[j] = gv[j] / sqrtf(q[j] * invM - m * m + BN_EPS);
        sh[j] = bv[j] - m * sc[j];
    }
    for (long r = blockIdx.x * 8 + rh; r < M; r += (long)gridDim.x * 8) {
        float4 v = *(float4*)(X + r * Dd + c);
        v.x = fmaxf(fmaf(v.x, sc[0], sh[0]), 0.f);
        v.y = fmaxf(fmaf(v.y, sc[1], sh[1]), 0.f);
        v.z = fmaxf(fmaf(v.z, sc[2], sh[2]), 0.f);
        v.w = fmaxf(fmaf(v.w, sc[3], sh[3]), 0.f);
        *(float4*)(X + r * Dd + c) = v;
    }
}

// ---------------------------------------------------------------- launch
extern "C" void kernel_launch(void* const* d_in, const int* in_sizes, int n_in,
                              void* d_out, int out_size, void* d_ws, size_t ws_size,
                              hipStream_t stream) {
    const float* x            = (const float*)d_in[0];
    const int*   node_in      = (const int*)d_in[1];
    const int*   node_out     = (const int*)d_in[2];
    const int*   relation     = (const int*)d_in[3];
    const float* edge_weight  = (const float*)d_in[4];
    const float* edge_feature = (const float*)d_in[5];
    const float* l1_Wlin  = (const float*)d_in[6];
    const float* l1_Wself = (const float*)d_in[8];
    const float* l1_Wedge = (const float*)d_in[10];
    const float* l1_bedge = (const float*)d_in[11];
    const float* l1_g     = (const float*)d_in[12];
    const float* l1_b     = (const float*)d_in[13];
    const float* l2_Wlin  = (const float*)d_in[14];
    const float* l2_Wself = (const float*)d_in[16];
    const float* l2_Wedge = (const float*)d_in[18];
    const float* l2_bedge = (const float*)d_in[19];
    const float* l2_g     = (const float*)d_in[20];
    const float* l2_b     = (const float*)d_in[21];
    float* out = (float*)d_out;

    // workspace layout (~166 MB)
    u16* u_bf       = (u16*)d_ws;                     // NR*128 bf16 (head doubles as aggef fp32 temp)
    float* aggef_f32 = (float*)d_ws;                  // NR*32 fp32 temp (overlaps u_bf head)
    u16* h          = u_bf + (long)NR * Dd;           // Nn*128 bf16
    u16* x_bf       = h + (long)Nn * Dd;              // Nn*128 bf16
    u16* aggef      = x_bf + (long)Nn * Dd;           // NR*32 bf16
    u16* Bt         = aggef + (long)NR * EDd;         // 11*16384 bf16
    float* deg      = (float*)(Bt + 11 * 16384);      // NR
    int*   cnt      = (int*)(deg + NR);               // NR
    int*   base     = cnt + NR;                       // NR
    int*   ni_s     = base + NR;                      // Ee
    float* ew_s     = (float*)(ni_s + Ee);            // Ee
    int*   partials = (int*)(ew_s + Ee);              // 1024
    float* stats    = (float*)(partials + 1024);      // 2*NREP*256

    const int NB1 = (NR + 1023) / 1024;               // 391

    // ---- prep
    hipMemsetAsync(deg, 0, sizeof(float) * NR, stream);
    hipMemsetAsync(cnt, 0, sizeof(int) * NR, stream);
    hipMemsetAsync(stats, 0, sizeof(float) * 2 * NREP * 256, stream);
    hipMemsetAsync(aggef_f32, 0, sizeof(float) * (long)NR * EDd, stream);
    k_deg<<<(Ee + 255) / 256, 256, 0, stream>>>(node_out, relation, edge_weight, deg, cnt);
    k_scan1<<<NB1, 256, 0, stream>>>(cnt, base, partials);
    k_scan2<<<1, 512, 0, stream>>>(partials, NB1);
    k_scan3<<<NB1, 256, 0, stream>>>(base, partials);
    k_scatter<<<(Ee + 255) / 256, 256, 0, stream>>>(node_in, node_out, relation, edge_weight,
                                                    deg, base, ni_s, ew_s);
    k_aggef<<<Ee / 8, 256, 0, stream>>>(node_out, relation, edge_weight, deg, edge_feature,
                                        aggef_f32);
    k_cvt<<<((long)NR * EDd / 4 + 255) / 256, 256, 0, stream>>>(aggef_f32, aggef, (long)NR * EDd);
    k_cvt<<<((long)Nn * Dd / 4 + 255) / 256, 256, 0, stream>>>(x, x_bf, (long)Nn * Dd);
    k_prepB<<<(11 * 16384 + 255) / 256, 256, 0, stream>>>(l1_Wlin, l1_Wself, l2_Wlin, l2_Wself, Bt);

    // ---- layer 1
    k_agg<<<4096, 256, 0, stream>>>(x_bf, base, cnt, ni_s, ew_s, aggef, l1_Wedge, l1_bedge, u_bf);
    k_gemm_l1<<<(Nn + 63) / 64, 256, 0, stream>>>(u_bf, x_bf, Bt, h, stats);
    k_bn_apply_bf<<<512, 256, 0, stream>>>(h, stats, l1_g, l1_b, Nn);

    // ---- layer 2
    k_agg<<<4096, 256, 0, stream>>>(h, base, cnt, ni_s, ew_s, aggef, l2_Wedge, l2_bedge, u_bf);
    k_gemm_l2<<<NR / 128, 256, 0, stream>>>(u_bf, h, Bt + 9 * 16384, out, stats + NREP * 256);
    k_bn_apply_f32<<<2048, 256, 0, stream>>>(out, stats + NREP * 256, l2_g, l2_b, NR);
}